// Round 6
// baseline (596.709 us; speedup 1.0000x reference)
//
#include <hip/hip_runtime.h>

#define D_MODEL 2048
#define SEQ     2048
#define BATCH   4
#define MTOT    (BATCH * SEQ)   // 8192
#define NQKV    (3 * D_MODEL)   // 6144

typedef __attribute__((ext_vector_type(8))) short bf16x8;
typedef __attribute__((ext_vector_type(8))) unsigned short ushort8;
typedef __attribute__((ext_vector_type(4))) float floatx4;

__device__ __forceinline__ unsigned short f2b(float f) {
    unsigned x = __builtin_bit_cast(unsigned, f);
    x += 0x7fffu + ((x >> 16) & 1u);   // round-to-nearest-even
    return (unsigned short)(x >> 16);
}

__device__ __forceinline__ void storeC(float* p, float v) { *p = v; }
__device__ __forceinline__ void storeC(unsigned short* p, float v) { *p = f2b(v); }

__device__ __forceinline__ void gload_lds16(const void* g, void* l) {
    __builtin_amdgcn_global_load_lds(
        (const __attribute__((address_space(1))) void*)g,
        (__attribute__((address_space(3))) void*)l,
        16, 0, 0);
}

// ---------------------------------------------------------------------------
// 256x256 BT GEMM, m201-shape 4-phase/K-tile schedule (z-batched):
// C[m,n] = sum_k A[m,k]*B[n,k] (+bias)(*scale). A,B bf16 k-major. BK=64,
// 8 waves (2M x 4N), per-wave C = 128x64, 16 MFMA (2mi x 4ni x 2ks) / phase.
// Phase shape (reads pre-issued; clean MFMA burst):
//   { ds_reads(4 or 12); stage gloads; [lgkmcnt(8) @P0];
//     s_barrier; lgkmcnt(0); sched_barrier(0);       // rule 18
//     setprio(1); 16 MFMA; setprio(0); [vmcnt]; s_barrier }
// R5 AUDIT FIX: uniform 2-gload/phase + vmcnt(4) was UNSATISFIABLE — P0
// consumes 3 halves (Bh0,Bh1,Ah0) but only 2 could be forced in time
// (A(kt)h0 staged P2(kt-1) was forced only at P0(kt)-end, AFTER its read).
// Rebalanced staging: whole next tile in the first two phases of tile kt:
//   P0: B(kt+1)h0 + A(kt+1)h0 (4 gloads) -> slot O
//   P1: B(kt+1)h1 + A(kt+1)h1 (4 gloads) -> slot O
//   P2, P3: no staging.
// Waits (producer-side, BEFORE the phase-end barrier; a wave's vmcnt covers
// only its own loads so the wait must precede the barrier releasing readers):
//   P0-end: vmcnt(4)  — forces A(kt)h1 (leaves this phase's 4 in flight)
//   P3-end: vmcnt(2)  — forces B(kt+1)+A(kt+1)h0 (leaves A(kt+1)h1)
// Force ledger (steady): Bh0/Ah0 issued P0, forced P3-end (3 phases slack);
// Bh1 issued P1, forced P3-end (2 phases); Ah1 issued P1, forced P0(next)-end
// (3 phases). All consumed >=1 barrier after force: B+Ah0 read P0(next),
// Ah1 read P2(next). Slack >=2 phases (~1200cy) vs ~900cy HBM latency.
// Death schedule: slot O regions last read in tile kt-1 (Bs[O]: P0; As[O][0]:
// P1 q1; As[O][1]: P3 q3), each drained by its reader's lgkmcnt(0) >=1
// barrier before the overwrite issue in tile kt. OK.
// Tail: last K-tile peeled (M=1): no stages; vmcnt(0) @P0-end forces
// A(NK-1)h1 (B+Ah0 were forced at P3(NK-2)-end).
// Prologue: stage tile0 (8 gloads), vmcnt(0), barrier.
// Requires NK even, NK >= 4 (all call sites: K=2048, NK=32).
// NOTE: default raster, no XCD swizzle (prior session: swizzle tripled FETCH).
// ---------------------------------------------------------------------------
#define BAR() do { asm volatile("" ::: "memory");                             \
                   __builtin_amdgcn_s_barrier();                              \
                   asm volatile("" ::: "memory"); } while (0)
#define VMW(N) asm volatile("s_waitcnt vmcnt(" #N ")" ::: "memory")
#define LKW(N) asm volatile("s_waitcnt lgkmcnt(" #N ")" ::: "memory")

#define MFMA16(q)                                                             \
    __builtin_amdgcn_s_setprio(1);                                            \
    _Pragma("unroll") for (int ks = 0; ks < 2; ++ks)                          \
    _Pragma("unroll") for (int mi = 0; mi < 2; ++mi)                          \
    _Pragma("unroll") for (int ni = 0; ni < 4; ++ni)                          \
        acc[(q) * 2 + mi][ni] = __builtin_amdgcn_mfma_f32_16x16x32_bf16(      \
            af[mi][ks], bf[ni][ks], acc[(q) * 2 + mi][ni], 0, 0, 0);          \
    __builtin_amdgcn_s_setprio(0);

// M: 0 = steady, 1 = last K-tile (kt = NK-1)
#define KTILE(KT, S, O, M)                                                    \
  {                                                                           \
    /* P0: frags B(full)+A(q0); stage B(kt+1)h0 + A(kt+1)h0 */                \
    ldBF(S); ldAF(S, 0);                                                      \
    if (M == 0) { stB((KT) + 1, 0, 0, O); stB((KT) + 1, 0, 1, O);             \
                  stA((KT) + 1, 0, 0, O); stA((KT) + 1, 0, 1, O); }           \
    LKW(8);                                                                   \
    BAR();                                                                    \
    LKW(0); __builtin_amdgcn_sched_barrier(0);                                \
    MFMA16(0)                                                                 \
    if (M == 0) { VMW(4); } else { VMW(0); }                                  \
    BAR();                                                                    \
    /* P1: frags A(q1); stage B(kt+1)h1 + A(kt+1)h1 */                        \
    ldAF(S, 1);                                                               \
    if (M == 0) { stB((KT) + 1, 1, 0, O); stB((KT) + 1, 1, 1, O);             \
                  stA((KT) + 1, 1, 0, O); stA((KT) + 1, 1, 1, O); }           \
    BAR();                                                                    \
    LKW(0); __builtin_amdgcn_sched_barrier(0);                                \
    MFMA16(1)                                                                 \
    BAR();                                                                    \
    /* P2: frags A(q2) */                                                     \
    ldAF(S, 2);                                                               \
    BAR();                                                                    \
    LKW(0); __builtin_amdgcn_sched_barrier(0);                                \
    MFMA16(2)                                                                 \
    BAR();                                                                    \
    /* P3: frags A(q3) */                                                     \
    ldAF(S, 3);                                                               \
    BAR();                                                                    \
    LKW(0); __builtin_amdgcn_sched_barrier(0);                                \
    MFMA16(3)                                                                 \
    if (M == 0) { VMW(2); BAR(); }                                            \
  }

template <int EPI, typename CT>
__global__ __launch_bounds__(512, 2) void gemm256(
    const unsigned short* __restrict__ A, int lda, long long strA,
    const unsigned short* __restrict__ B, int ldb, long long strB,
    CT* __restrict__ C, int ldc, long long strC,
    int K, const float* __restrict__ bias, float scale)
{
    // [slot][half][128 rows x 64 k] each; 64 KiB A + 64 KiB B = 128 KiB
    __shared__ __align__(16) unsigned short As[2][2][128 * 64];
    __shared__ __align__(16) unsigned short Bs[2][2][128 * 64];

    const int t = threadIdx.x;
    const int w = t >> 6, l = t & 63;
    const int wg_m = w >> 2, wg_n = w & 3;       // 2 x 4 wave grid
    const int quad = l >> 4, r16 = l & 15, sw = l & 7;
    const int cA0 = (quad ^ sw) * 8;             // ks0 swizzled col (elems)
    const int cA1 = ((4 + quad) ^ sw) * 8;       // ks1

    const int bz = blockIdx.z;
    A += (long long)bz * strA;
    B += (long long)bz * strB;
    C += (long long)bz * strC;

    const long long tM = (long long)blockIdx.y * 256;
    const long long tN = (long long)blockIdx.x * 256;

    // staging: thread t -> granule row r0 = t>>3 (0..63), slot s = t&7.
    // LDS(r,s) holds global k-chunk s^(r&7) (involution swizzle).
    const int r0 = t >> 3;
    const int kx = ((t & 7) ^ (r0 & 7)) * 8;
    const unsigned short* gA = A + (tM + r0) * (long long)lda + kx;
    const unsigned short* gB = B + (tN + r0) * (long long)ldb + kx;

    // one granule (64 LDS rows = 8KB) per call; wave w writes rows [w*8,+8)
    // A half h: LDS[sl][h] row R = g*64+rr <-> global row g*128 + h*64 + rr
    auto stA = [&](int kt, int h, int g, int sl) {
        gload_lds16(gA + (long long)(g * 128 + h * 64) * lda + kt * 64,
                    &As[sl][h][g * 4096 + w * 512]);
    };
    // B half h: LDS[sl][h] row R <-> global row h*128 + R
    auto stB = [&](int kt, int h, int g, int sl) {
        gload_lds16(gB + (long long)(h * 128 + g * 64) * ldb + kt * 64,
                    &Bs[sl][h][g * 4096 + w * 512]);
    };

    bf16x8 af[2][2], bf[4][2];
    auto ldAF = [&](int sl, int q) {
        const unsigned short* base = &As[sl][q >> 1][0];
#pragma unroll
        for (int mi = 0; mi < 2; ++mi) {
            const int r = (wg_m * 64 + (q & 1) * 32 + mi * 16 + r16) * 64;
            af[mi][0] = *(const bf16x8*)&base[r + cA0];
            af[mi][1] = *(const bf16x8*)&base[r + cA1];
        }
    };
    auto ldBF = [&](int sl) {
        const unsigned short* base = &Bs[sl][wg_n >> 1][0];
#pragma unroll
        for (int ni = 0; ni < 4; ++ni) {
            const int r = ((wg_n & 1) * 64 + ni * 16 + r16) * 64;
            bf[ni][0] = *(const bf16x8*)&base[r + cA0];
            bf[ni][1] = *(const bf16x8*)&base[r + cA1];
        }
    };

    floatx4 acc[8][4];
#pragma unroll
    for (int i = 0; i < 8; ++i)
#pragma unroll
        for (int j = 0; j < 4; ++j)
            acc[i][j] = (floatx4){0.f, 0.f, 0.f, 0.f};

    const int NK = K >> 6;   // even, >= 4 at all call sites

    // prologue: stage tile 0 complete (8 gloads), drain, barrier.
    stB(0, 0, 0, 0); stB(0, 0, 1, 0); stB(0, 1, 0, 0); stB(0, 1, 1, 0);
    stA(0, 0, 0, 0); stA(0, 0, 1, 0); stA(0, 1, 0, 0); stA(0, 1, 1, 0);
    VMW(0);                                   // MY tile-0 loads landed
    BAR();                                    // => ALL waves' tile-0 landed

    int kt = 0;
    for (; kt + 4 <= NK; kt += 2) {           // steady pairs: kt = 0..NK-4
        KTILE(kt, 0, 1, 0)
        KTILE(kt + 1, 1, 0, 0)
    }
    KTILE(NK - 2, 0, 1, 0)                    // stages tile NK-1
    KTILE(NK - 1, 1, 0, 1)                    // last (no stages, vmcnt(0)@P0)

    // C/D layout: col = lane&15, row = (lane>>4)*4 + reg
#pragma unroll
    for (int mi = 0; mi < 8; ++mi) {
#pragma unroll
        for (int ni = 0; ni < 4; ++ni) {
            const long long row = tM + wg_m * 128 + mi * 16 + quad * 4;
            const int col = (int)tN + wg_n * 64 + ni * 16 + r16;
            float badd = 0.f;
            if (EPI == 0) badd = bias[col];
#pragma unroll
            for (int r = 0; r < 4; ++r) {
                float v = acc[mi][ni][r] + badd;
                if (EPI == 1) v *= scale;
                storeC(&C[(row + r) * ldc + col], v);
            }
        }
    }
}

// f32 -> bf16 bulk convert, 8 elems/thread (n divisible by 2048)
__global__ void cvt_f32_bf16(const float* __restrict__ in,
                             unsigned short* __restrict__ out, long long n)
{
    long long i = ((long long)blockIdx.x * 256 + threadIdx.x) * 8;
    if (i + 7 < n) {
        float4 a = *(const float4*)(in + i);
        float4 b = *(const float4*)(in + i + 4);
        ushort8 o = {f2b(a.x), f2b(a.y), f2b(a.z), f2b(a.w),
                     f2b(b.x), f2b(b.y), f2b(b.z), f2b(b.w)};
        *(ushort8*)(out + i) = o;
    }
}

// W_qkv f32 [2048, 6144] (f = 3*d + sel fastest) -> Wqkv_t bf16 [6144, 2048],
// Wqkv_t[sel*2048 + d][k] = W_qkv[k][3*d + sel].  Tile: 64 k x 32 d (96 cols).
__global__ void deint_wqkv(const float* __restrict__ W,
                           unsigned short* __restrict__ Wt)
{
    __shared__ unsigned short t2[96][72];   // row stride 144B (16B-aligned)
    const int d0 = blockIdx.x * 32;
    const int k0 = blockIdx.y * 64;
    const int t = threadIdx.x;

#pragma unroll
    for (int it = 0; it < 24; ++it) {
        int i = t + it * 256;               // 0..6143 over 64 rows x 96 cols
        int r = i / 96, c = i - r * 96;
        t2[c][r] = f2b(W[(long long)(k0 + r) * NQKV + 3 * d0 + c]);
    }
    __syncthreads();

#pragma unroll
    for (int rnd = 0; rnd < 3; ++rnd) {
        int c  = (t >> 3) + rnd * 32;       // 0..95
        int kc = t & 7;
        int dx = c / 3, sel = c - 3 * dx;
        *(ushort8*)&Wt[(long long)(sel * 2048 + d0 + dx) * D_MODEL + k0 + kc * 8] =
            *(const ushort8*)&t2[c][kc * 8];
    }
}

// W_fc f32 [2048, 2048] -> Wfc_t bf16, Wfc_t[n][k] = W_fc[k][n]. Tile 64x64.
__global__ void transpose_wfc(const float* __restrict__ W,
                              unsigned short* __restrict__ Wt)
{
    __shared__ unsigned short t2[64][72];
    const int n0 = blockIdx.x * 64;
    const int k0 = blockIdx.y * 64;
    const int t = threadIdx.x;

#pragma unroll
    for (int it = 0; it < 16; ++it) {
        int i = t + it * 256;               // 64 rows x 64 cols
        int r = i >> 6, c = i & 63;
        t2[c][r] = f2b(W[(long long)(k0 + r) * D_MODEL + n0 + c]);
    }
    __syncthreads();

#pragma unroll
    for (int rnd = 0; rnd < 2; ++rnd) {
        int c  = (t >> 3) + rnd * 32;
        int kc = t & 7;
        *(ushort8*)&Wt[(long long)(n0 + c) * D_MODEL + k0 + kc * 8] =
            *(const ushort8*)&t2[c][kc * 8];
    }
}

// bias deinterleave (f32 -> f32): bias_qkv_t[sel*2048+d] = bqkv[3*d+sel]
__global__ void prep_bias(const float* __restrict__ bqkv,
                          const float* __restrict__ bfc,
                          float* __restrict__ bias_qkv_t,
                          float* __restrict__ bias_fc)
{
    int i = blockIdx.x * 256 + threadIdx.x;
    if (i < NQKV) {
        int sel = i >> 11, d = i & 2047;
        bias_qkv_t[i] = bqkv[3 * d + sel];
    } else if (i < NQKV + D_MODEL) {
        bias_fc[i - NQKV] = bfc[i - NQKV];
    }
}

extern "C" void kernel_launch(void* const* d_in, const int* in_sizes, int n_in,
                              void* d_out, int out_size, void* d_ws, size_t ws_size,
                              hipStream_t stream)
{
    (void)in_sizes; (void)n_in; (void)out_size;

    const float* x    = (const float*)d_in[0];
    const float* Wqkv = (const float*)d_in[1];
    const float* bqkv = (const float*)d_in[2];
    const float* Wfc  = (const float*)d_in[3];
    const float* bfc  = (const float*)d_in[4];
    float* out = (float*)d_out;

    char* ws = (char*)d_ws;
    size_t off = 0;
    auto alloc = [&](size_t bytes) {
        void* p = ws + off;
        off += (bytes + 255) & ~(size_t)255;
        return p;
    };

    const float scale = 0.02209708691207961f;  // 2048^-0.5
    const long long nx = (long long)MTOT * D_MODEL;  // 16.8M elems

    const size_t NEED_BATCHED = (size_t)(33554432ull + 8388608ull + 25165824ull
                                + 100663296ull + 33554432ull + 65536ull);

    if (ws_size >= NEED_BATCHED) {
        unsigned short* xb     = (unsigned short*)alloc((size_t)MTOT * D_MODEL * 2);
        unsigned short* Wfc_t  = (unsigned short*)alloc((size_t)D_MODEL * D_MODEL * 2);
        unsigned short* Wqkv_t = (unsigned short*)alloc((size_t)NQKV * D_MODEL * 2);
        unsigned short* QKV    = (unsigned short*)alloc((size_t)MTOT * NQKV * 2);
        unsigned short* S      = (unsigned short*)alloc((size_t)BATCH * SEQ * SEQ * 2);
        float* bias_qkv = (float*)alloc((size_t)NQKV * 4);
        float* bias_fc  = (float*)alloc((size_t)D_MODEL * 4);
        unsigned short* Abuf = xb;   // xb dead after stage 1

        cvt_f32_bf16<<<(int)(nx / 2048), 256, 0, stream>>>(x, xb, nx);
        deint_wqkv<<<dim3(64, 32), 256, 0, stream>>>(Wqkv, Wqkv_t);
        transpose_wfc<<<dim3(32, 32), 256, 0, stream>>>(Wfc, Wfc_t);
        prep_bias<<<32, 256, 0, stream>>>(bqkv, bfc, bias_qkv, bias_fc);

        const long long sQKV = (long long)SEQ * NQKV;
        const long long sS   = (long long)SEQ * SEQ;

        // 1) QKV = xb @ Wqkv_t^T + bias   [8192 x 6144]
        gemm256<0, unsigned short><<<dim3(NQKV / 256, MTOT / 256, 1), 512, 0, stream>>>(
            xb, D_MODEL, 0, Wqkv_t, D_MODEL, 0, QKV, NQKV, 0, D_MODEL, bias_qkv, 1.f);
        // 2) S_b = Q_b @ K_b^T * scale    z-batched [2048 x 2048] x4
        gemm256<1, unsigned short><<<dim3(SEQ / 256, SEQ / 256, BATCH), 512, 0, stream>>>(
            QKV, NQKV, sQKV, QKV + D_MODEL, NQKV, sQKV, S, SEQ, sS, D_MODEL, nullptr, scale);
        // 3) A_b = S_b @ V_b^T            z-batched [2048 x 2048] x4
        gemm256<2, unsigned short><<<dim3(SEQ / 256, SEQ / 256, BATCH), 512, 0, stream>>>(
            S, SEQ, sS, QKV + 2 * D_MODEL, NQKV, sQKV, Abuf, SEQ, sS, SEQ, nullptr, 1.f);
        // 4) out = A @ Wfc_t^T + bias_fc  [8192 x 2048] f32 out
        gemm256<0, float><<<dim3(D_MODEL / 256, MTOT / 256, 1), 512, 0, stream>>>(
            Abuf, SEQ, 0, Wfc_t, D_MODEL, 0, out, D_MODEL, 0, SEQ, bias_fc, 1.f);
    } else {
        // Fallback: per-batch (~110 MB)
        unsigned short* xb     = (unsigned short*)alloc((size_t)MTOT * D_MODEL * 2);
        unsigned short* Wqkv_t = (unsigned short*)alloc((size_t)NQKV * D_MODEL * 2);
        unsigned short* Wfc_t  = (unsigned short*)alloc((size_t)D_MODEL * D_MODEL * 2);
        unsigned short* QKVb   = (unsigned short*)alloc((size_t)SEQ * NQKV * 2);
        unsigned short* Sb     = (unsigned short*)alloc((size_t)SEQ * SEQ * 2);
        unsigned short* Ab     = (unsigned short*)alloc((size_t)SEQ * SEQ * 2);
        float* bias_qkv = (float*)alloc((size_t)NQKV * 4);
        float* bias_fc  = (float*)alloc((size_t)D_MODEL * 4);

        cvt_f32_bf16<<<(int)(nx / 2048), 256, 0, stream>>>(x, xb, nx);
        deint_wqkv<<<dim3(64, 32), 256, 0, stream>>>(Wqkv, Wqkv_t);
        transpose_wfc<<<dim3(32, 32), 256, 0, stream>>>(Wfc, Wfc_t);
        prep_bias<<<32, 256, 0, stream>>>(bqkv, bfc, bias_qkv, bias_fc);

        for (int b = 0; b < BATCH; ++b) {
            const unsigned short* xb_b = xb + (long long)b * SEQ * D_MODEL;
            float* out_b = out + (long long)b * SEQ * D_MODEL;
            gemm256<0, unsigned short><<<dim3(NQKV / 256, SEQ / 256, 1), 512, 0, stream>>>(
                xb_b, D_MODEL, 0, Wqkv_t, D_MODEL, 0, QKVb, NQKV, 0, D_MODEL, bias_qkv, 1.f);
            gemm256<1, unsigned short><<<dim3(SEQ / 256, SEQ / 256, 1), 512, 0, stream>>>(
                QKVb, NQKV, 0, QKVb + D_MODEL, NQKV, 0, Sb, SEQ, 0, D_MODEL, nullptr, scale);
            gemm256<2, unsigned short><<<dim3(SEQ / 256, SEQ / 256, 1), 512, 0, stream>>>(
                Sb, SEQ, 0, QKVb + 2 * D_MODEL, NQKV, 0, Ab, SEQ, 0, SEQ, nullptr, 1.f);
            gemm256<0, float><<<dim3(D_MODEL / 256, SEQ / 256, 1), 512, 0, stream>>>(
                Ab, SEQ, 0, Wfc_t, D_MODEL, 0, out_b, D_MODEL, 0, SEQ, bias_fc, 1.f);
        }
    }
}

// Round 7
// 542.510 us; speedup vs baseline: 1.0999x; 1.0999x over previous
//
#include <hip/hip_runtime.h>

#define D_MODEL 2048
#define SEQ     2048
#define BATCH   4
#define MTOT    (BATCH * SEQ)   // 8192
#define NQKV    (3 * D_MODEL)   // 6144

typedef __attribute__((ext_vector_type(8))) short bf16x8;
typedef __attribute__((ext_vector_type(8))) unsigned short ushort8;
typedef __attribute__((ext_vector_type(4))) float floatx4;

__device__ __forceinline__ unsigned short f2b(float f) {
    unsigned x = __builtin_bit_cast(unsigned, f);
    x += 0x7fffu + ((x >> 16) & 1u);   // round-to-nearest-even
    return (unsigned short)(x >> 16);
}

__device__ __forceinline__ void storeC(float* p, float v) { *p = v; }
__device__ __forceinline__ void storeC(unsigned short* p, float v) { *p = f2b(v); }

__device__ __forceinline__ void gload_lds16(const void* g, void* l) {
    __builtin_amdgcn_global_load_lds(
        (const __attribute__((address_space(1))) void*)g,
        (__attribute__((address_space(3))) void*)l,
        16, 0, 0);
}

// ---------------------------------------------------------------------------
// 256x256 BT GEMM, 2-phase/K-tile FUSED schedule (z-batched):
// C[m,n] = sum_k A[m,k]*B[n,k] (+bias)(*scale). A,B bf16 k-major. BK=64,
// 8 waves (2M x 4N), per-wave C = 128x64.
// Session ladder: R1(8bar,drain)=42.6% | R3(8bar,read-ahead)=42.4% |
// R4(4bar,FUSED)=47.6% | R6(8bar,drain+preissue)=36.8% MfmaUtil.
// => barrier count dominates at 1 block/CU (no cross-block overlap; every
// barrier costs full-block skew) and forced lgkmcnt(0) drains serialize the
// LDS pipe against MFMA. This version: R4's fused interval (reads + staging
// + MFMA in ONE barrier interval, compiler-counted lgkm waits, NO drains),
// barriers halved to 2/K-tile. Phase h computes C-half h (4mi x 4ni x 2ks =
// 32 MFMA); reads at phase start (P0: B-full 8 + A-h0 8 = 16 ds_read_b128;
// P1: A-h1 8); staging 4 gloads/phase:
//   P0: B(kt+1) h0g0,h0g1,h1g0,h1g1 -> slot O
//   P1: A(kt+1) h0g0,h0g1,h1g0,h1g1 -> slot O
// Waits (producer-side, BEFORE the phase-end barrier — a wave's vmcnt covers
// only its own loads, so the wait must precede the barrier releasing
// consumers). Issue simulation (prologue drains to 0):
//   P0-end: vmcnt(4) — forces A(kt)h1 (leaves B(kt+1) 4 in flight)
//   P1-end: vmcnt(2) — forces B(kt+1)+A(kt+1)h0 (leaves A(kt+1)h1)
// Slack >=1 phase (~1300cy) vs ~900cy HBM latency for every granule; each
// consumed granule forced >=1 barrier before its read. Death: overwritten
// regions' last readers drain via their own phase MFMAs (counted lgkm)
// before that phase's end barrier; overwrite issues >=2 barriers later.
// Tail: last K-tile peeled (M=1): no stages; vmcnt(0) @P0-end forces
// A(NK-1)h1 (vmcnt(4) would NO-OP on the drained pipe — R2-class trap).
// Prologue: stage tile0 (8 gloads), vmcnt(0), barrier.
// Requires NK even, NK >= 4 (all call sites: K=2048, NK=32).
// NOTE: default raster, no XCD swizzle (prior session: swizzle tripled FETCH).
// ---------------------------------------------------------------------------
#define BAR() do { asm volatile("" ::: "memory");                             \
                   __builtin_amdgcn_s_barrier();                              \
                   asm volatile("" ::: "memory"); } while (0)
#define VMW(N) asm volatile("s_waitcnt vmcnt(" #N ")" ::: "memory")

#define MFMA32(h)                                                             \
    __builtin_amdgcn_s_setprio(1);                                            \
    _Pragma("unroll") for (int ks = 0; ks < 2; ++ks)                          \
    _Pragma("unroll") for (int mi = 0; mi < 4; ++mi)                          \
    _Pragma("unroll") for (int ni = 0; ni < 4; ++ni)                          \
        acc[(h) * 4 + mi][ni] = __builtin_amdgcn_mfma_f32_16x16x32_bf16(      \
            af[mi][ks], bf[ni][ks], acc[(h) * 4 + mi][ni], 0, 0, 0);          \
    __builtin_amdgcn_s_setprio(0);

// M: 0 = steady, 1 = last K-tile (kt = NK-1)
#define KTILE2(KT, S, O, M)                                                   \
  {                                                                           \
    /* P0: frags B(full)+A(h0); stage B(kt+1) full; 32 MFMA (acc 0..3) */     \
    ldBF(S); ldAF2(S, 0);                                                     \
    if (M == 0) { stB((KT) + 1, 0, 0, O); stB((KT) + 1, 0, 1, O);             \
                  stB((KT) + 1, 1, 0, O); stB((KT) + 1, 1, 1, O); }           \
    MFMA32(0)                                                                 \
    if (M == 0) { VMW(4); } else { VMW(0); }                                  \
    BAR();                                                                    \
    /* P1: frags A(h1); stage A(kt+1) full; 32 MFMA (acc 4..7) */             \
    ldAF2(S, 1);                                                              \
    if (M == 0) { stA((KT) + 1, 0, 0, O); stA((KT) + 1, 0, 1, O);             \
                  stA((KT) + 1, 1, 0, O); stA((KT) + 1, 1, 1, O); }           \
    MFMA32(1)                                                                 \
    if (M == 0) { VMW(2); BAR(); }                                            \
  }

template <int EPI, typename CT>
__global__ __launch_bounds__(512, 2) void gemm256(
    const unsigned short* __restrict__ A, int lda, long long strA,
    const unsigned short* __restrict__ B, int ldb, long long strB,
    CT* __restrict__ C, int ldc, long long strC,
    int K, const float* __restrict__ bias, float scale)
{
    // [slot][half][128 rows x 64 k] each; 64 KiB A + 64 KiB B = 128 KiB
    __shared__ __align__(16) unsigned short As[2][2][128 * 64];
    __shared__ __align__(16) unsigned short Bs[2][2][128 * 64];

    const int t = threadIdx.x;
    const int w = t >> 6, l = t & 63;
    const int wg_m = w >> 2, wg_n = w & 3;       // 2 x 4 wave grid
    const int quad = l >> 4, r16 = l & 15, sw = l & 7;
    const int cA0 = (quad ^ sw) * 8;             // ks0 swizzled col (elems)
    const int cA1 = ((4 + quad) ^ sw) * 8;       // ks1

    const int bz = blockIdx.z;
    A += (long long)bz * strA;
    B += (long long)bz * strB;
    C += (long long)bz * strC;

    const long long tM = (long long)blockIdx.y * 256;
    const long long tN = (long long)blockIdx.x * 256;

    // staging: thread t -> granule row r0 = t>>3 (0..63), slot s = t&7.
    // LDS(r,s) holds global k-chunk s^(r&7) (involution swizzle).
    const int r0 = t >> 3;
    const int kx = ((t & 7) ^ (r0 & 7)) * 8;
    const unsigned short* gA = A + (tM + r0) * (long long)lda + kx;
    const unsigned short* gB = B + (tN + r0) * (long long)ldb + kx;

    // one granule (64 LDS rows = 8KB) per call; wave w writes rows [w*8,+8)
    // A half h: LDS[sl][h] row R = g*64+rr <-> global row g*128 + h*64 + rr
    auto stA = [&](int kt, int h, int g, int sl) {
        gload_lds16(gA + (long long)(g * 128 + h * 64) * lda + kt * 64,
                    &As[sl][h][g * 4096 + w * 512]);
    };
    // B half h: LDS[sl][h] row R <-> global row h*128 + R
    auto stB = [&](int kt, int h, int g, int sl) {
        gload_lds16(gB + (long long)(h * 128 + g * 64) * ldb + kt * 64,
                    &Bs[sl][h][g * 4096 + w * 512]);
    };

    // fragment reads. A rows for acc[h*4+mi]: global wg_m*128 + h*64 + mi*16
    // = As[sl][h] LDS row wg_m*64 + mi*16 + r16 (g = wg_m).
    bf16x8 af[4][2], bf[4][2];
    auto ldAF2 = [&](int sl, int h) {
        const unsigned short* base = &As[sl][h][0];
#pragma unroll
        for (int mi = 0; mi < 4; ++mi) {
            const int r = (wg_m * 64 + mi * 16 + r16) * 64;
            af[mi][0] = *(const bf16x8*)&base[r + cA0];
            af[mi][1] = *(const bf16x8*)&base[r + cA1];
        }
    };
    auto ldBF = [&](int sl) {
        const unsigned short* base = &Bs[sl][wg_n >> 1][0];
#pragma unroll
        for (int ni = 0; ni < 4; ++ni) {
            const int r = ((wg_n & 1) * 64 + ni * 16 + r16) * 64;
            bf[ni][0] = *(const bf16x8*)&base[r + cA0];
            bf[ni][1] = *(const bf16x8*)&base[r + cA1];
        }
    };

    floatx4 acc[8][4];
#pragma unroll
    for (int i = 0; i < 8; ++i)
#pragma unroll
        for (int j = 0; j < 4; ++j)
            acc[i][j] = (floatx4){0.f, 0.f, 0.f, 0.f};

    const int NK = K >> 6;   // even, >= 4 at all call sites

    // prologue: stage tile 0 complete (8 gloads), drain, barrier.
    stB(0, 0, 0, 0); stB(0, 0, 1, 0); stB(0, 1, 0, 0); stB(0, 1, 1, 0);
    stA(0, 0, 0, 0); stA(0, 0, 1, 0); stA(0, 1, 0, 0); stA(0, 1, 1, 0);
    VMW(0);                                   // MY tile-0 loads landed
    BAR();                                    // => ALL waves' tile-0 landed

    int kt = 0;
    for (; kt + 4 <= NK; kt += 2) {           // steady pairs: kt = 0..NK-4
        KTILE2(kt, 0, 1, 0)
        KTILE2(kt + 1, 1, 0, 0)
    }
    KTILE2(NK - 2, 0, 1, 0)                   // stages tile NK-1
    KTILE2(NK - 1, 1, 0, 1)                   // last (no stages, vmcnt(0)@P0)

    // C/D layout: col = lane&15, row = (lane>>4)*4 + reg
#pragma unroll
    for (int mi = 0; mi < 8; ++mi) {
#pragma unroll
        for (int ni = 0; ni < 4; ++ni) {
            const long long row = tM + wg_m * 128 + mi * 16 + quad * 4;
            const int col = (int)tN + wg_n * 64 + ni * 16 + r16;
            float badd = 0.f;
            if (EPI == 0) badd = bias[col];
#pragma unroll
            for (int r = 0; r < 4; ++r) {
                float v = acc[mi][ni][r] + badd;
                if (EPI == 1) v *= scale;
                storeC(&C[(row + r) * ldc + col], v);
            }
        }
    }
}

// f32 -> bf16 bulk convert, 8 elems/thread (n divisible by 2048)
__global__ void cvt_f32_bf16(const float* __restrict__ in,
                             unsigned short* __restrict__ out, long long n)
{
    long long i = ((long long)blockIdx.x * 256 + threadIdx.x) * 8;
    if (i + 7 < n) {
        float4 a = *(const float4*)(in + i);
        float4 b = *(const float4*)(in + i + 4);
        ushort8 o = {f2b(a.x), f2b(a.y), f2b(a.z), f2b(a.w),
                     f2b(b.x), f2b(b.y), f2b(b.z), f2b(b.w)};
        *(ushort8*)(out + i) = o;
    }
}

// W_qkv f32 [2048, 6144] (f = 3*d + sel fastest) -> Wqkv_t bf16 [6144, 2048],
// Wqkv_t[sel*2048 + d][k] = W_qkv[k][3*d + sel].  Tile: 64 k x 32 d (96 cols).
__global__ void deint_wqkv(const float* __restrict__ W,
                           unsigned short* __restrict__ Wt)
{
    __shared__ unsigned short t2[96][72];   // row stride 144B (16B-aligned)
    const int d0 = blockIdx.x * 32;
    const int k0 = blockIdx.y * 64;
    const int t = threadIdx.x;

#pragma unroll
    for (int it = 0; it < 24; ++it) {
        int i = t + it * 256;               // 0..6143 over 64 rows x 96 cols
        int r = i / 96, c = i - r * 96;
        t2[c][r] = f2b(W[(long long)(k0 + r) * NQKV + 3 * d0 + c]);
    }
    __syncthreads();

#pragma unroll
    for (int rnd = 0; rnd < 3; ++rnd) {
        int c  = (t >> 3) + rnd * 32;       // 0..95
        int kc = t & 7;
        int dx = c / 3, sel = c - 3 * dx;
        *(ushort8*)&Wt[(long long)(sel * 2048 + d0 + dx) * D_MODEL + k0 + kc * 8] =
            *(const ushort8*)&t2[c][kc * 8];
    }
}

// W_fc f32 [2048, 2048] -> Wfc_t bf16, Wfc_t[n][k] = W_fc[k][n]. Tile 64x64.
__global__ void transpose_wfc(const float* __restrict__ W,
                              unsigned short* __restrict__ Wt)
{
    __shared__ unsigned short t2[64][72];
    const int n0 = blockIdx.x * 64;
    const int k0 = blockIdx.y * 64;
    const int t = threadIdx.x;

#pragma unroll
    for (int it = 0; it < 16; ++it) {
        int i = t + it * 256;               // 64 rows x 64 cols
        int r = i >> 6, c = i & 63;
        t2[c][r] = f2b(W[(long long)(k0 + r) * D_MODEL + n0 + c]);
    }
    __syncthreads();

#pragma unroll
    for (int rnd = 0; rnd < 2; ++rnd) {
        int c  = (t >> 3) + rnd * 32;
        int kc = t & 7;
        *(ushort8*)&Wt[(long long)(n0 + c) * D_MODEL + k0 + kc * 8] =
            *(const ushort8*)&t2[c][kc * 8];
    }
}

// bias deinterleave (f32 -> f32): bias_qkv_t[sel*2048+d] = bqkv[3*d+sel]
__global__ void prep_bias(const float* __restrict__ bqkv,
                          const float* __restrict__ bfc,
                          float* __restrict__ bias_qkv_t,
                          float* __restrict__ bias_fc)
{
    int i = blockIdx.x * 256 + threadIdx.x;
    if (i < NQKV) {
        int sel = i >> 11, d = i & 2047;
        bias_qkv_t[i] = bqkv[3 * d + sel];
    } else if (i < NQKV + D_MODEL) {
        bias_fc[i - NQKV] = bfc[i - NQKV];
    }
}

extern "C" void kernel_launch(void* const* d_in, const int* in_sizes, int n_in,
                              void* d_out, int out_size, void* d_ws, size_t ws_size,
                              hipStream_t stream)
{
    (void)in_sizes; (void)n_in; (void)out_size;

    const float* x    = (const float*)d_in[0];
    const float* Wqkv = (const float*)d_in[1];
    const float* bqkv = (const float*)d_in[2];
    const float* Wfc  = (const float*)d_in[3];
    const float* bfc  = (const float*)d_in[4];
    float* out = (float*)d_out;

    char* ws = (char*)d_ws;
    size_t off = 0;
    auto alloc = [&](size_t bytes) {
        void* p = ws + off;
        off += (bytes + 255) & ~(size_t)255;
        return p;
    };

    const float scale = 0.02209708691207961f;  // 2048^-0.5
    const long long nx = (long long)MTOT * D_MODEL;  // 16.8M elems

    const size_t NEED_BATCHED = (size_t)(33554432ull + 8388608ull + 25165824ull
                                + 100663296ull + 33554432ull + 65536ull);

    if (ws_size >= NEED_BATCHED) {
        unsigned short* xb     = (unsigned short*)alloc((size_t)MTOT * D_MODEL * 2);
        unsigned short* Wfc_t  = (unsigned short*)alloc((size_t)D_MODEL * D_MODEL * 2);
        unsigned short* Wqkv_t = (unsigned short*)alloc((size_t)NQKV * D_MODEL * 2);
        unsigned short* QKV    = (unsigned short*)alloc((size_t)MTOT * NQKV * 2);
        unsigned short* S      = (unsigned short*)alloc((size_t)BATCH * SEQ * SEQ * 2);
        float* bias_qkv = (float*)alloc((size_t)NQKV * 4);
        float* bias_fc  = (float*)alloc((size_t)D_MODEL * 4);
        unsigned short* Abuf = xb;   // xb dead after stage 1

        cvt_f32_bf16<<<(int)(nx / 2048), 256, 0, stream>>>(x, xb, nx);
        deint_wqkv<<<dim3(64, 32), 256, 0, stream>>>(Wqkv, Wqkv_t);
        transpose_wfc<<<dim3(32, 32), 256, 0, stream>>>(Wfc, Wfc_t);
        prep_bias<<<32, 256, 0, stream>>>(bqkv, bfc, bias_qkv, bias_fc);

        const long long sQKV = (long long)SEQ * NQKV;
        const long long sS   = (long long)SEQ * SEQ;

        // 1) QKV = xb @ Wqkv_t^T + bias   [8192 x 6144]
        gemm256<0, unsigned short><<<dim3(NQKV / 256, MTOT / 256, 1), 512, 0, stream>>>(
            xb, D_MODEL, 0, Wqkv_t, D_MODEL, 0, QKV, NQKV, 0, D_MODEL, bias_qkv, 1.f);
        // 2) S_b = Q_b @ K_b^T * scale    z-batched [2048 x 2048] x4
        gemm256<1, unsigned short><<<dim3(SEQ / 256, SEQ / 256, BATCH), 512, 0, stream>>>(
            QKV, NQKV, sQKV, QKV + D_MODEL, NQKV, sQKV, S, SEQ, sS, D_MODEL, nullptr, scale);
        // 3) A_b = S_b @ V_b^T            z-batched [2048 x 2048] x4
        gemm256<2, unsigned short><<<dim3(SEQ / 256, SEQ / 256, BATCH), 512, 0, stream>>>(
            S, SEQ, sS, QKV + 2 * D_MODEL, NQKV, sQKV, Abuf, SEQ, sS, SEQ, nullptr, 1.f);
        // 4) out = A @ Wfc_t^T + bias_fc  [8192 x 2048] f32 out
        gemm256<0, float><<<dim3(D_MODEL / 256, MTOT / 256, 1), 512, 0, stream>>>(
            Abuf, SEQ, 0, Wfc_t, D_MODEL, 0, out, D_MODEL, 0, SEQ, bias_fc, 1.f);
    } else {
        // Fallback: per-batch (~110 MB)
        unsigned short* xb     = (unsigned short*)alloc((size_t)MTOT * D_MODEL * 2);
        unsigned short* Wqkv_t = (unsigned short*)alloc((size_t)NQKV * D_MODEL * 2);
        unsigned short* Wfc_t  = (unsigned short*)alloc((size_t)D_MODEL * D_MODEL * 2);
        unsigned short* QKVb   = (unsigned short*)alloc((size_t)SEQ * NQKV * 2);
        unsigned short* Sb     = (unsigned short*)alloc((size_t)SEQ * SEQ * 2);
        unsigned short* Ab     = (unsigned short*)alloc((size_t)SEQ * SEQ * 2);
        float* bias_qkv = (float*)alloc((size_t)NQKV * 4);
        float* bias_fc  = (float*)alloc((size_t)D_MODEL * 4);

        cvt_f32_bf16<<<(int)(nx / 2048), 256, 0, stream>>>(x, xb, nx);
        deint_wqkv<<<dim3(64, 32), 256, 0, stream>>>(Wqkv, Wqkv_t);
        transpose_wfc<<<dim3(32, 32), 256, 0, stream>>>(Wfc, Wfc_t);
        prep_bias<<<32, 256, 0, stream>>>(bqkv, bfc, bias_qkv, bias_fc);

        for (int b = 0; b < BATCH; ++b) {
            const unsigned short* xb_b = xb + (long long)b * SEQ * D_MODEL;
            float* out_b = out + (long long)b * SEQ * D_MODEL;
            gemm256<0, unsigned short><<<dim3(NQKV / 256, SEQ / 256, 1), 512, 0, stream>>>(
                xb_b, D_MODEL, 0, Wqkv_t, D_MODEL, 0, QKVb, NQKV, 0, D_MODEL, bias_qkv, 1.f);
            gemm256<1, unsigned short><<<dim3(SEQ / 256, SEQ / 256, 1), 512, 0, stream>>>(
                QKVb, NQKV, 0, QKVb + D_MODEL, NQKV, 0, Sb, SEQ, 0, D_MODEL, nullptr, scale);
            gemm256<2, unsigned short><<<dim3(SEQ / 256, SEQ / 256, 1), 512, 0, stream>>>(
                Sb, SEQ, 0, QKVb + 2 * D_MODEL, NQKV, 0, Ab, SEQ, 0, SEQ, nullptr, 1.f);
            gemm256<0, float><<<dim3(D_MODEL / 256, SEQ / 256, 1), 512, 0, stream>>>(
                Ab, SEQ, 0, Wfc_t, D_MODEL, 0, out_b, D_MODEL, 0, SEQ, bias_fc, 1.f);
        }
    }
}